// Round 1
// baseline (2847.563 us; speedup 1.0000x reference)
//
#include <hip/hip_runtime.h>

#define D 128
#define RB 32

// ---------------------------------------------------------------------------
// Pass 1: edge scatter.  32 lanes per edge, float4 per lane (128 floats/edge).
// agg[dst] += w * x[src] via fp32 global atomics.
// ---------------------------------------------------------------------------
__global__ __launch_bounds__(256) void scatter_kernel(
    const float* __restrict__ x, const int* __restrict__ ei,
    const float* __restrict__ ew, float* __restrict__ agg, int E) {
  long long t = (long long)blockIdx.x * blockDim.x + threadIdx.x;
  int lane = (int)(t & 31);
  long long e = t >> 5;
  if (e >= E) return;
  int s = ei[e];
  int d = ei[(long long)E + e];
  float w = ew[e];
  const float4* xs = (const float4*)(x + (long long)s * D);
  float4 v = xs[lane];
  float* ap = agg + (long long)d * D + lane * 4;
  atomicAdd(ap + 0, v.x * w);
  atomicAdd(ap + 1, v.y * w);
  atomicAdd(ap + 2, v.z * w);
  atomicAdd(ap + 3, v.w * w);
}

// ---------------------------------------------------------------------------
// Pass 2: out = agg @ W^T + b.  fp32 vector GEMM (no fp32 MFMA on CDNA4).
// Block: 256 threads, 32 rows x 128 cols.  W chunk staged transposed in LDS
// (row padded 128->132: bank = (4k+j)%32, float4-aligned, conflict-free on
// the compute-side b128 reads).  agg tile reads are wave-uniform -> LDS
// broadcast, no padding needed.  4x4 register blocking per thread.
// ---------------------------------------------------------------------------
__global__ __launch_bounds__(256) void gemm_kernel(
    const float* __restrict__ agg, const float* __restrict__ W,
    const float* __restrict__ b, float* __restrict__ out, int N) {
  __shared__ float sWt[64][132];  // [k][j] transposed W chunk, padded
  __shared__ float sA[RB][64];    // [r][k] agg tile chunk

  int tid = threadIdx.x;
  int c0 = (tid & 31) * 4;   // 4 consecutive output cols
  int r0 = (tid >> 5) * 4;   // 4 rows
  int rowBase = blockIdx.x * RB;

  float acc[4][4];
#pragma unroll
  for (int i = 0; i < 4; i++)
#pragma unroll
    for (int j = 0; j < 4; j++) acc[i][j] = 0.f;

  for (int kh = 0; kh < 2; kh++) {
    __syncthreads();
    // Load W chunk transposed: sWt[k][j] = W[j][kh*64+k].  Global reads
    // coalesced along k; LDS write conflicts (8-way) are amortized.
    for (int i = tid; i < 64 * 128; i += 256) {
      int j = i >> 6;
      int k = i & 63;
      sWt[k][j] = W[j * 128 + kh * 64 + k];
    }
    // Load agg tile chunk (coalesced along k).
    for (int i = tid; i < RB * 64; i += 256) {
      int r = i >> 6;
      int k = i & 63;
      int row = rowBase + r;
      sA[r][k] = (row < N) ? agg[(long long)row * 128 + kh * 64 + k] : 0.f;
    }
    __syncthreads();

#pragma unroll 4
    for (int k = 0; k < 64; k++) {
      float4 wt = *(const float4*)&sWt[k][c0];  // conflict-free b128
#pragma unroll
      for (int i = 0; i < 4; i++) {
        float a = sA[r0 + i][k];  // wave-uniform -> broadcast
        acc[i][0] += a * wt.x;
        acc[i][1] += a * wt.y;
        acc[i][2] += a * wt.z;
        acc[i][3] += a * wt.w;
      }
    }
  }

  float4 bb = *(const float4*)(b + c0);
#pragma unroll
  for (int i = 0; i < 4; i++) {
    int row = rowBase + r0 + i;
    if (row < N) {
      float4 o = {acc[i][0] + bb.x, acc[i][1] + bb.y, acc[i][2] + bb.z,
                  acc[i][3] + bb.w};
      *(float4*)(out + (long long)row * D + c0) = o;
    }
  }
}

extern "C" void kernel_launch(void* const* d_in, const int* in_sizes, int n_in,
                              void* d_out, int out_size, void* d_ws,
                              size_t ws_size, hipStream_t stream) {
  const float* x = (const float*)d_in[0];
  const int* ei = (const int*)d_in[1];   // edge_index [2, E] (int32)
  const float* ew = (const float*)d_in[2];
  const float* W = (const float*)d_in[3];
  const float* b = (const float*)d_in[4];

  int N = in_sizes[0] / D;  // 100000
  int E = in_sizes[2];      // 1600000

  float* agg = (float*)d_ws;  // [N, 128] scratch, 51.2 MB
  float* out = (float*)d_out;

  // Workspace is re-poisoned to 0xAA before every launch -> must zero here.
  hipMemsetAsync(agg, 0, (size_t)N * D * sizeof(float), stream);

  long long threads = (long long)E * 32;
  int blocks = (int)((threads + 255) / 256);
  scatter_kernel<<<blocks, 256, 0, stream>>>(x, ei, ew, agg, E);

  gemm_kernel<<<(N + RB - 1) / RB, 256, 0, stream>>>(agg, W, b, out, N);
}

// Round 2
// 495.025 us; speedup vs baseline: 5.7524x; 5.7524x over previous
//
#include <hip/hip_runtime.h>

#define D 128
#define RB 32

// ---------------------------------------------------------------------------
// Phase A: histogram of destination degrees. 1.6M int atomics (cheap vs the
// 204.8M fp32 atomics of the old scatter).
// ---------------------------------------------------------------------------
__global__ __launch_bounds__(256) void hist_kernel(const int* __restrict__ ei,
                                                   int* __restrict__ deg, int E) {
  int e = blockIdx.x * 256 + threadIdx.x;
  if (e >= E) return;
  atomicAdd(&deg[ei[E + e]], 1);
}

// ---------------------------------------------------------------------------
// Phase B: exclusive prefix sum over deg[N].  3 tiny kernels.
// ---------------------------------------------------------------------------
__global__ __launch_bounds__(256) void scan_block(const int* __restrict__ deg,
                                                  int* __restrict__ offs,
                                                  int* __restrict__ blockSums,
                                                  int N) {
  __shared__ int s[256];
  int t = threadIdx.x;
  int i = blockIdx.x * 256 + t;
  int v = (i < N) ? deg[i] : 0;
  s[t] = v;
  __syncthreads();
  for (int off = 1; off < 256; off <<= 1) {
    int add = (t >= off) ? s[t - off] : 0;
    __syncthreads();
    s[t] += add;
    __syncthreads();
  }
  if (i < N) offs[i] = s[t] - v;  // exclusive
  if (t == 255) blockSums[blockIdx.x] = s[255];
}

__global__ __launch_bounds__(512) void scan_sums(int* __restrict__ blockSums,
                                                 int NB) {
  __shared__ int s[512];
  int t = threadIdx.x;
  int v = (t < NB) ? blockSums[t] : 0;
  s[t] = v;
  __syncthreads();
  for (int off = 1; off < 512; off <<= 1) {
    int add = (t >= off) ? s[t - off] : 0;
    __syncthreads();
    s[t] += add;
    __syncthreads();
  }
  if (t < NB) blockSums[t] = s[t] - v;  // exclusive block offsets
}

__global__ __launch_bounds__(256) void add_offs(int* __restrict__ offs,
                                                const int* __restrict__ blockSums,
                                                int* __restrict__ cursor, int N) {
  int i = blockIdx.x * 256 + threadIdx.x;
  if (i < N) {
    int o = offs[i] + blockSums[blockIdx.x];
    offs[i] = o;
    cursor[i] = o;
  }
}

// ---------------------------------------------------------------------------
// Phase C: scatter edges into per-dst buckets.  Packed (src, weight) 8B.
// ---------------------------------------------------------------------------
__global__ __launch_bounds__(256) void fill_bucket(const int* __restrict__ ei,
                                                   const float* __restrict__ ew,
                                                   int* __restrict__ cursor,
                                                   int2* __restrict__ bucket,
                                                   int E) {
  int e = blockIdx.x * 256 + threadIdx.x;
  if (e >= E) return;
  int s = ei[e];
  int d = ei[E + e];
  float w = ew[e];
  int p = atomicAdd(&cursor[d], 1);
  bucket[p] = make_int2(s, __float_as_int(w));
}

// ---------------------------------------------------------------------------
// Phase D: gather.  One wave64 per node; lane holds 2 floats of the row
// (float2 load = 512 B/edge across the wave, coalesced).  agg row written
// exactly once -> no fp atomics anywhere.
// ---------------------------------------------------------------------------
__global__ __launch_bounds__(256) void gather_kernel(
    const float* __restrict__ x, const int2* __restrict__ bucket,
    const int* __restrict__ offs, const int* __restrict__ deg,
    float* __restrict__ agg, int N) {
  int wave = threadIdx.x >> 6;
  int lane = threadIdx.x & 63;
  int node = blockIdx.x * 4 + wave;
  if (node >= N) return;
  int start = offs[node];
  int cnt = deg[node];
  const float2* xv = (const float2*)x;
  float2 acc = {0.f, 0.f};
  int i = 0;
  // 2-edge unroll for a little ILP; TLP (many resident waves) hides the rest.
  for (; i + 2 <= cnt; i += 2) {
    int2 b0 = bucket[start + i];
    int2 b1 = bucket[start + i + 1];
    float w0 = __int_as_float(b0.y);
    float w1 = __int_as_float(b1.y);
    float2 v0 = xv[(long long)b0.x * 64 + lane];
    float2 v1 = xv[(long long)b1.x * 64 + lane];
    acc.x += w0 * v0.x + w1 * v1.x;
    acc.y += w0 * v0.y + w1 * v1.y;
  }
  if (i < cnt) {
    int2 b0 = bucket[start + i];
    float w0 = __int_as_float(b0.y);
    float2 v0 = xv[(long long)b0.x * 64 + lane];
    acc.x += w0 * v0.x;
    acc.y += w0 * v0.y;
  }
  ((float2*)agg)[(long long)node * 64 + lane] = acc;
}

// ---------------------------------------------------------------------------
// Phase E: out = agg @ W^T + b.  Unchanged from R1 (not the bottleneck yet).
// ---------------------------------------------------------------------------
__global__ __launch_bounds__(256) void gemm_kernel(
    const float* __restrict__ agg, const float* __restrict__ W,
    const float* __restrict__ b, float* __restrict__ out, int N) {
  __shared__ float sWt[64][132];
  __shared__ float sA[RB][64];

  int tid = threadIdx.x;
  int c0 = (tid & 31) * 4;
  int r0 = (tid >> 5) * 4;
  int rowBase = blockIdx.x * RB;

  float acc[4][4];
#pragma unroll
  for (int i = 0; i < 4; i++)
#pragma unroll
    for (int j = 0; j < 4; j++) acc[i][j] = 0.f;

  for (int kh = 0; kh < 2; kh++) {
    __syncthreads();
    for (int i = tid; i < 64 * 128; i += 256) {
      int j = i >> 6;
      int k = i & 63;
      sWt[k][j] = W[j * 128 + kh * 64 + k];
    }
    for (int i = tid; i < RB * 64; i += 256) {
      int r = i >> 6;
      int k = i & 63;
      int row = rowBase + r;
      sA[r][k] = (row < N) ? agg[(long long)row * 128 + kh * 64 + k] : 0.f;
    }
    __syncthreads();

#pragma unroll 4
    for (int k = 0; k < 64; k++) {
      float4 wt = *(const float4*)&sWt[k][c0];
#pragma unroll
      for (int i = 0; i < 4; i++) {
        float a = sA[r0 + i][k];
        acc[i][0] += a * wt.x;
        acc[i][1] += a * wt.y;
        acc[i][2] += a * wt.z;
        acc[i][3] += a * wt.w;
      }
    }
  }

  float4 bb = *(const float4*)(b + c0);
#pragma unroll
  for (int i = 0; i < 4; i++) {
    int row = rowBase + r0 + i;
    if (row < N) {
      float4 o = {acc[i][0] + bb.x, acc[i][1] + bb.y, acc[i][2] + bb.z,
                  acc[i][3] + bb.w};
      *(float4*)(out + (long long)row * D + c0) = o;
    }
  }
}

extern "C" void kernel_launch(void* const* d_in, const int* in_sizes, int n_in,
                              void* d_out, int out_size, void* d_ws,
                              size_t ws_size, hipStream_t stream) {
  const float* x = (const float*)d_in[0];
  const int* ei = (const int*)d_in[1];
  const float* ew = (const float*)d_in[2];
  const float* W = (const float*)d_in[3];
  const float* b = (const float*)d_in[4];

  int N = in_sizes[0] / D;  // 100000
  int E = in_sizes[2];      // 1600000
  int NB = (N + 255) / 256;
  int Npad = NB * 256;

  // Workspace layout (all 16B-aligned by construction):
  //   deg[Npad] | offs[Npad] | cursor[Npad] | blockSums[512] | bucket[E] (int2) | agg[N*128]
  int* deg = (int*)d_ws;
  int* offs = deg + Npad;
  int* cursor = offs + Npad;
  int* blockSums = cursor + Npad;
  int2* bucket = (int2*)(blockSums + 512);
  float* agg = (float*)(bucket + E);

  // Only deg needs zeroing; everything else is fully written before read.
  hipMemsetAsync(deg, 0, (size_t)Npad * sizeof(int), stream);

  int eBlocks = (E + 255) / 256;
  hist_kernel<<<eBlocks, 256, 0, stream>>>(ei, deg, E);
  scan_block<<<NB, 256, 0, stream>>>(deg, offs, blockSums, N);
  scan_sums<<<1, 512, 0, stream>>>(blockSums, NB);
  add_offs<<<NB, 256, 0, stream>>>(offs, blockSums, cursor, N);
  fill_bucket<<<eBlocks, 256, 0, stream>>>(ei, ew, cursor, bucket, E);
  gather_kernel<<<(N + 3) / 4, 256, 0, stream>>>(x, bucket, offs, deg, agg, N);
  gemm_kernel<<<(N + RB - 1) / RB, 256, 0, stream>>>(agg, W, b, (float*)d_out, N);
}

// Round 3
// 483.335 us; speedup vs baseline: 5.8915x; 1.0242x over previous
//
#include <hip/hip_runtime.h>

#define D 128
#define RB 32

// ---------------------------------------------------------------------------
// K1 (fused): blocks [0, GB) compute y = x @ W^T  (NO bias — bias is added
// once per node in the gather; baking it into y would scale it by edge
// weights).  Blocks [GB, GB+HB) histogram dst degrees.  The two jobs are
// independent; fusing them hides the histogram's atomic latency under the
// GEMM's FMA pipeline instead of paying a serial dispatch.
// ---------------------------------------------------------------------------
__global__ __launch_bounds__(256) void k1_gemm_hist(
    const float* __restrict__ x, const float* __restrict__ W,
    float* __restrict__ y, const int* __restrict__ ei, int* __restrict__ deg,
    int N, int E, int GB) {
  if (blockIdx.x >= GB) {
    // --- histogram part ---
    int e = (blockIdx.x - GB) * 256 + threadIdx.x;
    if (e < E) atomicAdd(&deg[ei[E + e]], 1);
    return;
  }
  // --- GEMM part: 32 rows x 128 cols per block, 4x4 register blocking ---
  __shared__ float sWt[64][132];  // [k][j], padded row -> conflict-free b128
  __shared__ float sA[RB][64];

  int tid = threadIdx.x;
  int c0 = (tid & 31) * 4;
  int r0 = (tid >> 5) * 4;
  int rowBase = blockIdx.x * RB;

  float acc[4][4];
#pragma unroll
  for (int i = 0; i < 4; i++)
#pragma unroll
    for (int j = 0; j < 4; j++) acc[i][j] = 0.f;

  for (int kh = 0; kh < 2; kh++) {
    __syncthreads();
    for (int i = tid; i < 64 * 128; i += 256) {
      int j = i >> 6;
      int k = i & 63;
      sWt[k][j] = W[j * 128 + kh * 64 + k];
    }
    for (int i = tid; i < RB * 64; i += 256) {
      int r = i >> 6;
      int k = i & 63;
      int row = rowBase + r;
      sA[r][k] = (row < N) ? x[(long long)row * 128 + kh * 64 + k] : 0.f;
    }
    __syncthreads();

#pragma unroll 4
    for (int k = 0; k < 64; k++) {
      float4 wt = *(const float4*)&sWt[k][c0];
#pragma unroll
      for (int i = 0; i < 4; i++) {
        float a = sA[r0 + i][k];
        acc[i][0] += a * wt.x;
        acc[i][1] += a * wt.y;
        acc[i][2] += a * wt.z;
        acc[i][3] += a * wt.w;
      }
    }
  }

#pragma unroll
  for (int i = 0; i < 4; i++) {
    int row = rowBase + r0 + i;
    if (row < N) {
      float4 o = {acc[i][0], acc[i][1], acc[i][2], acc[i][3]};
      *(float4*)(y + (long long)row * D + c0) = o;
    }
  }
}

// ---------------------------------------------------------------------------
// Scan (3 tiny kernels) — unchanged.
// ---------------------------------------------------------------------------
__global__ __launch_bounds__(256) void scan_block(const int* __restrict__ deg,
                                                  int* __restrict__ offs,
                                                  int* __restrict__ blockSums,
                                                  int N) {
  __shared__ int s[256];
  int t = threadIdx.x;
  int i = blockIdx.x * 256 + t;
  int v = (i < N) ? deg[i] : 0;
  s[t] = v;
  __syncthreads();
  for (int off = 1; off < 256; off <<= 1) {
    int add = (t >= off) ? s[t - off] : 0;
    __syncthreads();
    s[t] += add;
    __syncthreads();
  }
  if (i < N) offs[i] = s[t] - v;
  if (t == 255) blockSums[blockIdx.x] = s[255];
}

__global__ __launch_bounds__(512) void scan_sums(int* __restrict__ blockSums,
                                                 int NB) {
  __shared__ int s[512];
  int t = threadIdx.x;
  int v = (t < NB) ? blockSums[t] : 0;
  s[t] = v;
  __syncthreads();
  for (int off = 1; off < 512; off <<= 1) {
    int add = (t >= off) ? s[t - off] : 0;
    __syncthreads();
    s[t] += add;
    __syncthreads();
  }
  if (t < NB) blockSums[t] = s[t] - v;
}

__global__ __launch_bounds__(256) void add_offs(int* __restrict__ offs,
                                                const int* __restrict__ blockSums,
                                                int* __restrict__ cursor, int N) {
  int i = blockIdx.x * 256 + threadIdx.x;
  if (i < N) {
    int o = offs[i] + blockSums[blockIdx.x];
    offs[i] = o;
    cursor[i] = o;
  }
}

// ---------------------------------------------------------------------------
// Fill: 4 edges per thread via int4/float4 loads -> 4 independent
// atomic->store chains in flight (the pass is latency-bound, not BW-bound:
// R2 showed 11% HBM, 0.4% VALU).  E is a multiple of 4 (1.6M).
// ---------------------------------------------------------------------------
__global__ __launch_bounds__(256) void fill_bucket(const int* __restrict__ ei,
                                                   const float* __restrict__ ew,
                                                   int* __restrict__ cursor,
                                                   int2* __restrict__ bucket,
                                                   int E) {
  int t = blockIdx.x * 256 + threadIdx.x;
  int e0 = t * 4;
  if (e0 >= E) return;
  int4 s4 = *(const int4*)(ei + e0);
  int4 d4 = *(const int4*)(ei + E + e0);
  float4 w4 = *(const float4*)(ew + e0);
  int p0 = atomicAdd(&cursor[d4.x], 1);
  int p1 = atomicAdd(&cursor[d4.y], 1);
  int p2 = atomicAdd(&cursor[d4.z], 1);
  int p3 = atomicAdd(&cursor[d4.w], 1);
  bucket[p0] = make_int2(s4.x, __float_as_int(w4.x));
  bucket[p1] = make_int2(s4.y, __float_as_int(w4.y));
  bucket[p2] = make_int2(s4.z, __float_as_int(w4.z));
  bucket[p3] = make_int2(s4.w, __float_as_int(w4.w));
}

// ---------------------------------------------------------------------------
// Gather: one wave64 per node, float2 per lane, 4-edge unroll (4 outstanding
// 512B row-gathers per wave).  Writes the FINAL output: out = sum w*y[src] + b.
// ---------------------------------------------------------------------------
__global__ __launch_bounds__(256) void gather_kernel(
    const float* __restrict__ y, const int2* __restrict__ bucket,
    const int* __restrict__ offs, const int* __restrict__ deg,
    const float* __restrict__ b, float* __restrict__ out, int N) {
  int wave = threadIdx.x >> 6;
  int lane = threadIdx.x & 63;
  int node = blockIdx.x * 4 + wave;
  if (node >= N) return;
  int start = offs[node];
  int cnt = deg[node];
  const float2* yv = (const float2*)y;
  float2 acc = {0.f, 0.f};
  int i = 0;
  for (; i + 4 <= cnt; i += 4) {
    int2 b0 = bucket[start + i];
    int2 b1 = bucket[start + i + 1];
    int2 b2 = bucket[start + i + 2];
    int2 b3 = bucket[start + i + 3];
    float2 v0 = yv[(long long)b0.x * 64 + lane];
    float2 v1 = yv[(long long)b1.x * 64 + lane];
    float2 v2 = yv[(long long)b2.x * 64 + lane];
    float2 v3 = yv[(long long)b3.x * 64 + lane];
    float w0 = __int_as_float(b0.y), w1 = __int_as_float(b1.y);
    float w2 = __int_as_float(b2.y), w3 = __int_as_float(b3.y);
    acc.x += w0 * v0.x + w1 * v1.x + w2 * v2.x + w3 * v3.x;
    acc.y += w0 * v0.y + w1 * v1.y + w2 * v2.y + w3 * v3.y;
  }
  for (; i < cnt; i++) {
    int2 b0 = bucket[start + i];
    float w0 = __int_as_float(b0.y);
    float2 v0 = yv[(long long)b0.x * 64 + lane];
    acc.x += w0 * v0.x;
    acc.y += w0 * v0.y;
  }
  float2 bb = ((const float2*)b)[lane];
  float2 o = {acc.x + bb.x, acc.y + bb.y};
  ((float2*)out)[(long long)node * 64 + lane] = o;
}

extern "C" void kernel_launch(void* const* d_in, const int* in_sizes, int n_in,
                              void* d_out, int out_size, void* d_ws,
                              size_t ws_size, hipStream_t stream) {
  const float* x = (const float*)d_in[0];
  const int* ei = (const int*)d_in[1];
  const float* ew = (const float*)d_in[2];
  const float* W = (const float*)d_in[3];
  const float* b = (const float*)d_in[4];

  int N = in_sizes[0] / D;  // 100000
  int E = in_sizes[2];      // 1600000
  int NB = (N + 255) / 256;
  int Npad = NB * 256;

  // Workspace: deg | offs | cursor | blockSums | bucket (int2) | y
  int* deg = (int*)d_ws;
  int* offs = deg + Npad;
  int* cursor = offs + Npad;
  int* blockSums = cursor + Npad;
  int2* bucket = (int2*)(blockSums + 512);
  float* y = (float*)(bucket + E);

  hipMemsetAsync(deg, 0, (size_t)Npad * sizeof(int), stream);

  int GB = (N + RB - 1) / RB;       // gemm blocks
  int HB = (E + 255) / 256;         // hist blocks
  k1_gemm_hist<<<GB + HB, 256, 0, stream>>>(x, W, y, ei, deg, N, E, GB);
  scan_block<<<NB, 256, 0, stream>>>(deg, offs, blockSums, N);
  scan_sums<<<1, 512, 0, stream>>>(blockSums, NB);
  add_offs<<<NB, 256, 0, stream>>>(offs, blockSums, cursor, N);
  fill_bucket<<<(E / 4 + 255) / 256, 256, 0, stream>>>(ei, ew, cursor, bucket, E);
  gather_kernel<<<(N + 3) / 4, 256, 0, stream>>>(y, bucket, offs, deg, b,
                                                 (float*)d_out, N);
}

// Round 4
// 423.261 us; speedup vs baseline: 6.7277x; 1.1419x over previous
//
#include <hip/hip_runtime.h>
#include <hip/hip_bf16.h>

#define D 128
#define RB 32

// ---------------------------------------------------------------------------
// K1 (fused): blocks [0, GB) compute y = x @ W^T stored as bf16 (RNE).
// y is internal-only: halves the gather's read traffic; final accumulation
// and output stay fp32.  Blocks [GB, GB+HB) histogram dst degrees (atomic
// latency hidden under the GEMM's FMA pipeline).
// ---------------------------------------------------------------------------
__global__ __launch_bounds__(256) void k1_gemm_hist(
    const float* __restrict__ x, const float* __restrict__ W,
    ushort* __restrict__ y, const int* __restrict__ ei, int* __restrict__ deg,
    int N, int E, int GB) {
  if (blockIdx.x >= GB) {
    int e = (blockIdx.x - GB) * 256 + threadIdx.x;
    if (e < E) atomicAdd(&deg[ei[E + e]], 1);
    return;
  }
  __shared__ float sWt[64][132];  // [k][j], padded -> conflict-free b128 reads
  __shared__ float sA[RB][64];

  int tid = threadIdx.x;
  int c0 = (tid & 31) * 4;
  int r0 = (tid >> 5) * 4;
  int rowBase = blockIdx.x * RB;

  float acc[4][4];
#pragma unroll
  for (int i = 0; i < 4; i++)
#pragma unroll
    for (int j = 0; j < 4; j++) acc[i][j] = 0.f;

  for (int kh = 0; kh < 2; kh++) {
    __syncthreads();
    for (int i = tid; i < 64 * 128; i += 256) {
      int j = i >> 6;
      int k = i & 63;
      sWt[k][j] = W[j * 128 + kh * 64 + k];
    }
    for (int i = tid; i < RB * 64; i += 256) {
      int r = i >> 6;
      int k = i & 63;
      int row = rowBase + r;
      sA[r][k] = (row < N) ? x[(long long)row * 128 + kh * 64 + k] : 0.f;
    }
    __syncthreads();

#pragma unroll 4
    for (int k = 0; k < 64; k++) {
      float4 wt = *(const float4*)&sWt[k][c0];
#pragma unroll
      for (int i = 0; i < 4; i++) {
        float a = sA[r0 + i][k];
        acc[i][0] += a * wt.x;
        acc[i][1] += a * wt.y;
        acc[i][2] += a * wt.z;
        acc[i][3] += a * wt.w;
      }
    }
  }

#pragma unroll
  for (int i = 0; i < 4; i++) {
    int row = rowBase + r0 + i;
    if (row < N) {
      ushort4 o;
      o.x = __hip_bfloat16_raw(__float2bfloat16(acc[i][0])).x;
      o.y = __hip_bfloat16_raw(__float2bfloat16(acc[i][1])).x;
      o.z = __hip_bfloat16_raw(__float2bfloat16(acc[i][2])).x;
      o.w = __hip_bfloat16_raw(__float2bfloat16(acc[i][3])).x;
      *(ushort4*)(y + (long long)row * D + c0) = o;
    }
  }
}

// ---------------------------------------------------------------------------
// Scan (3 tiny kernels).
// ---------------------------------------------------------------------------
__global__ __launch_bounds__(256) void scan_block(const int* __restrict__ deg,
                                                  int* __restrict__ offs,
                                                  int* __restrict__ blockSums,
                                                  int N) {
  __shared__ int s[256];
  int t = threadIdx.x;
  int i = blockIdx.x * 256 + t;
  int v = (i < N) ? deg[i] : 0;
  s[t] = v;
  __syncthreads();
  for (int off = 1; off < 256; off <<= 1) {
    int add = (t >= off) ? s[t - off] : 0;
    __syncthreads();
    s[t] += add;
    __syncthreads();
  }
  if (i < N) offs[i] = s[t] - v;
  if (t == 255) blockSums[blockIdx.x] = s[255];
}

__global__ __launch_bounds__(512) void scan_sums(int* __restrict__ blockSums,
                                                 int NB) {
  __shared__ int s[512];
  int t = threadIdx.x;
  int v = (t < NB) ? blockSums[t] : 0;
  s[t] = v;
  __syncthreads();
  for (int off = 1; off < 512; off <<= 1) {
    int add = (t >= off) ? s[t - off] : 0;
    __syncthreads();
    s[t] += add;
    __syncthreads();
  }
  if (t < NB) blockSums[t] = s[t] - v;
}

__global__ __launch_bounds__(256) void add_offs(int* __restrict__ offs,
                                                const int* __restrict__ blockSums,
                                                int* __restrict__ cursor, int N) {
  int i = blockIdx.x * 256 + threadIdx.x;
  if (i < N) {
    int o = offs[i] + blockSums[blockIdx.x];
    offs[i] = o;
    cursor[i] = o;
  }
}

// ---------------------------------------------------------------------------
// Fill: 1 edge/thread (R2 form — proven fastest; this pass is TLP-fed, the
// R3 4-edge unroll cut wave count 4x and regressed).
// ---------------------------------------------------------------------------
__global__ __launch_bounds__(256) void fill_bucket(const int* __restrict__ ei,
                                                   const float* __restrict__ ew,
                                                   int* __restrict__ cursor,
                                                   int2* __restrict__ bucket,
                                                   int E) {
  int e = blockIdx.x * 256 + threadIdx.x;
  if (e >= E) return;
  int s = ei[e];
  int d = ei[E + e];
  float w = ew[e];
  int p = atomicAdd(&cursor[d], 1);
  bucket[p] = make_int2(s, __float_as_int(w));
}

// ---------------------------------------------------------------------------
// Gather: one wave64 per node; lane reads one bf16x2 (4 B) of the 256 B row
// -> coalesced 4-line row reads, half of R3's bytes.  fp32 accumulate,
// fp32 output: out = sum w*y[src] + b.
// ---------------------------------------------------------------------------
__global__ __launch_bounds__(256) void gather_kernel(
    const ushort* __restrict__ y, const int2* __restrict__ bucket,
    const int* __restrict__ offs, const int* __restrict__ deg,
    const float* __restrict__ b, float* __restrict__ out, int N) {
  int wave = threadIdx.x >> 6;
  int lane = threadIdx.x & 63;
  int node = blockIdx.x * 4 + wave;
  if (node >= N) return;
  int start = offs[node];
  int cnt = deg[node];
  const ushort2* yv = (const ushort2*)y;
  float ax = 0.f, ay = 0.f;
  int i = 0;
  for (; i + 4 <= cnt; i += 4) {
    int2 b0 = bucket[start + i];
    int2 b1 = bucket[start + i + 1];
    int2 b2 = bucket[start + i + 2];
    int2 b3 = bucket[start + i + 3];
    ushort2 u0 = yv[(long long)b0.x * 64 + lane];
    ushort2 u1 = yv[(long long)b1.x * 64 + lane];
    ushort2 u2 = yv[(long long)b2.x * 64 + lane];
    ushort2 u3 = yv[(long long)b3.x * 64 + lane];
    float w0 = __int_as_float(b0.y), w1 = __int_as_float(b1.y);
    float w2 = __int_as_float(b2.y), w3 = __int_as_float(b3.y);
    ax += w0 * __uint_as_float((unsigned)u0.x << 16) +
          w1 * __uint_as_float((unsigned)u1.x << 16) +
          w2 * __uint_as_float((unsigned)u2.x << 16) +
          w3 * __uint_as_float((unsigned)u3.x << 16);
    ay += w0 * __uint_as_float((unsigned)u0.y << 16) +
          w1 * __uint_as_float((unsigned)u1.y << 16) +
          w2 * __uint_as_float((unsigned)u2.y << 16) +
          w3 * __uint_as_float((unsigned)u3.y << 16);
  }
  for (; i < cnt; i++) {
    int2 b0 = bucket[start + i];
    float w0 = __int_as_float(b0.y);
    ushort2 u0 = yv[(long long)b0.x * 64 + lane];
    ax += w0 * __uint_as_float((unsigned)u0.x << 16);
    ay += w0 * __uint_as_float((unsigned)u0.y << 16);
  }
  float2 bb = ((const float2*)b)[lane];
  float2 o = {ax + bb.x, ay + bb.y};
  ((float2*)out)[(long long)node * 64 + lane] = o;
}

extern "C" void kernel_launch(void* const* d_in, const int* in_sizes, int n_in,
                              void* d_out, int out_size, void* d_ws,
                              size_t ws_size, hipStream_t stream) {
  const float* x = (const float*)d_in[0];
  const int* ei = (const int*)d_in[1];
  const float* ew = (const float*)d_in[2];
  const float* W = (const float*)d_in[3];
  const float* b = (const float*)d_in[4];

  int N = in_sizes[0] / D;  // 100000
  int E = in_sizes[2];      // 1600000
  int NB = (N + 255) / 256;
  int Npad = NB * 256;

  // Workspace: deg | offs | cursor | blockSums | bucket (int2) | y (bf16)
  int* deg = (int*)d_ws;
  int* offs = deg + Npad;
  int* cursor = offs + Npad;
  int* blockSums = cursor + Npad;
  int2* bucket = (int2*)(blockSums + 512);
  ushort* y = (ushort*)(bucket + E);

  hipMemsetAsync(deg, 0, (size_t)Npad * sizeof(int), stream);

  int GB = (N + RB - 1) / RB;
  int HB = (E + 255) / 256;
  k1_gemm_hist<<<GB + HB, 256, 0, stream>>>(x, W, y, ei, deg, N, E, GB);
  scan_block<<<NB, 256, 0, stream>>>(deg, offs, blockSums, N);
  scan_sums<<<1, 512, 0, stream>>>(blockSums, NB);
  add_offs<<<NB, 256, 0, stream>>>(offs, blockSums, cursor, N);
  fill_bucket<<<(E + 255) / 256, 256, 0, stream>>>(ei, ew, cursor, bucket, E);
  gather_kernel<<<(N + 3) / 4, 256, 0, stream>>>(y, bucket, offs, deg, b,
                                                 (float*)d_out, N);
}

// Round 5
// 389.815 us; speedup vs baseline: 7.3049x; 1.0858x over previous
//
#include <hip/hip_runtime.h>
#include <hip/hip_bf16.h>

#define D 128
#define RT 64  // gemm rows per block

typedef __attribute__((ext_vector_type(8))) short short8;
typedef __attribute__((ext_vector_type(4))) float floatx4;

__device__ __forceinline__ ushort f2bf(float v) {
  __hip_bfloat16 h = __float2bfloat16(v);  // RNE
  return __hip_bfloat16_raw(h).x;
}

// ---------------------------------------------------------------------------
// K1 (fused): blocks [0, GB): y = bf16(x @ W^T) via 16x16x32 bf16 MFMA.
// 64 rows/block, 4 waves, each wave owns one 16-row tile x all 128 cols.
// sX/sW rows padded 128->136 bf16 (+16 B): keeps b128 frag reads 16B-aligned
// and banks at worst 2-way (free).  Blocks [GB, GB+HB): dst-degree histogram
// (atomic latency hidden under the GEMM blocks).
// ---------------------------------------------------------------------------
__global__ __launch_bounds__(256) void k1_gemm_hist(
    const float* __restrict__ x, const float* __restrict__ W,
    ushort* __restrict__ y, const int* __restrict__ ei, int* __restrict__ deg,
    int N, int E, int GB) {
  if (blockIdx.x >= GB) {
    int e = (blockIdx.x - GB) * 256 + threadIdx.x;
    if (e < E) atomicAdd(&deg[ei[E + e]], 1);
    return;
  }
  __shared__ __align__(16) ushort sX[RT * 136];
  __shared__ __align__(16) ushort sW[128 * 136];

  int tid = threadIdx.x;
  int rowBase = blockIdx.x * RT;

  // Stage W (128x128) -> bf16 LDS.  4096 float4 / 256 threads = 16 iters.
#pragma unroll
  for (int it = 0; it < 16; it++) {
    int i = tid + it * 256;
    int r = i >> 5;
    int c4 = i & 31;
    float4 v = *(const float4*)(W + r * 128 + c4 * 4);
    ushort4 o = make_ushort4(f2bf(v.x), f2bf(v.y), f2bf(v.z), f2bf(v.w));
    *(ushort4*)&sW[r * 136 + c4 * 4] = o;
  }
  // Stage x tile (64x128) -> bf16 LDS.  2048 float4 / 256 = 8 iters.
#pragma unroll
  for (int it = 0; it < 8; it++) {
    int i = tid + it * 256;
    int r = i >> 5;
    int c4 = i & 31;
    int row = rowBase + r;
    float4 v = (row < N) ? *(const float4*)(x + (long long)row * 128 + c4 * 4)
                         : make_float4(0.f, 0.f, 0.f, 0.f);
    ushort4 o = make_ushort4(f2bf(v.x), f2bf(v.y), f2bf(v.z), f2bf(v.w));
    *(ushort4*)&sX[r * 136 + c4 * 4] = o;
  }
  __syncthreads();

  int wv = tid >> 6;    // row-tile 0..3
  int lane = tid & 63;
  int m = lane & 15;    // A row within tile / B col within tile
  int q = lane >> 4;    // k-quad

  const ushort* aRow = &sX[(wv * 16 + m) * 136 + q * 8];
  const ushort* bRow = &sW[m * 136 + q * 8];

  floatx4 acc[8];
#pragma unroll
  for (int ct = 0; ct < 8; ct++) acc[ct] = (floatx4){0.f, 0.f, 0.f, 0.f};

#pragma unroll
  for (int ks = 0; ks < 4; ks++) {
    short8 a = *(const short8*)(aRow + ks * 32);
#pragma unroll
    for (int ct = 0; ct < 8; ct++) {
      short8 b = *(const short8*)(bRow + ct * 16 * 136 + ks * 32);
      acc[ct] = __builtin_amdgcn_mfma_f32_16x16x32_bf16(a, b, acc[ct], 0, 0, 0);
    }
  }

  // C/D layout (verified m89): col = lane&15, row = (lane>>4)*4 + reg.
  int row0 = rowBase + wv * 16 + q * 4;
#pragma unroll
  for (int r = 0; r < 4; r++) {
    int row = row0 + r;
    if (row < N) {
      ushort* yp = y + (long long)row * 128 + m;
#pragma unroll
      for (int ct = 0; ct < 8; ct++) yp[ct * 16] = f2bf(acc[ct][r]);
    }
  }
}

// ---------------------------------------------------------------------------
// Scan: block-level exclusive scan, then fused finish (each block reduces its
// own blockSums prefix — saves a dispatch).
// ---------------------------------------------------------------------------
__global__ __launch_bounds__(256) void scan_block(const int* __restrict__ deg,
                                                  int* __restrict__ offs,
                                                  int* __restrict__ blockSums,
                                                  int N) {
  __shared__ int s[256];
  int t = threadIdx.x;
  int i = blockIdx.x * 256 + t;
  int v = (i < N) ? deg[i] : 0;
  s[t] = v;
  __syncthreads();
  for (int off = 1; off < 256; off <<= 1) {
    int add = (t >= off) ? s[t - off] : 0;
    __syncthreads();
    s[t] += add;
    __syncthreads();
  }
  if (i < N) offs[i] = s[t] - v;
  if (t == 255) blockSums[blockIdx.x] = s[255];
}

__global__ __launch_bounds__(256) void scan_finish(int* __restrict__ offs,
                                                   const int* __restrict__ blockSums,
                                                   int* __restrict__ cursor,
                                                   int N) {
  __shared__ int s[256];
  int t = threadIdx.x;
  int acc = 0;
  for (int j = t; j < (int)blockIdx.x; j += 256) acc += blockSums[j];
  s[t] = acc;
  __syncthreads();
  for (int off = 128; off; off >>= 1) {
    if (t < off) s[t] += s[t + off];
    __syncthreads();
  }
  int pre = s[0];
  int i = blockIdx.x * 256 + t;
  if (i < N) {
    int o = offs[i] + pre;
    offs[i] = o;
    cursor[i] = o;
  }
}

// ---------------------------------------------------------------------------
// Fill: 1 edge/thread (TLP-fed; R3's 4-edge unroll regressed).
// ---------------------------------------------------------------------------
__global__ __launch_bounds__(256) void fill_bucket(const int* __restrict__ ei,
                                                   const float* __restrict__ ew,
                                                   int* __restrict__ cursor,
                                                   int2* __restrict__ bucket,
                                                   int E) {
  int e = blockIdx.x * 256 + threadIdx.x;
  if (e >= E) return;
  int s = ei[e];
  int d = ei[E + e];
  float w = ew[e];
  int p = atomicAdd(&cursor[d], 1);
  bucket[p] = make_int2(s, __float_as_int(w));
}

// ---------------------------------------------------------------------------
// Gather: one wave64 per node; lane reads bf16x2 (4 B) of each 256 B y-row.
// fp32 accumulate + bias; fp32 output.
// ---------------------------------------------------------------------------
__global__ __launch_bounds__(256) void gather_kernel(
    const ushort* __restrict__ y, const int2* __restrict__ bucket,
    const int* __restrict__ offs, const int* __restrict__ deg,
    const float* __restrict__ b, float* __restrict__ out, int N) {
  int wave = threadIdx.x >> 6;
  int lane = threadIdx.x & 63;
  int node = blockIdx.x * 4 + wave;
  if (node >= N) return;
  int start = offs[node];
  int cnt = deg[node];
  const ushort2* yv = (const ushort2*)y;
  float ax = 0.f, ay = 0.f;
  int i = 0;
  for (; i + 4 <= cnt; i += 4) {
    int2 b0 = bucket[start + i];
    int2 b1 = bucket[start + i + 1];
    int2 b2 = bucket[start + i + 2];
    int2 b3 = bucket[start + i + 3];
    ushort2 u0 = yv[(long long)b0.x * 64 + lane];
    ushort2 u1 = yv[(long long)b1.x * 64 + lane];
    ushort2 u2 = yv[(long long)b2.x * 64 + lane];
    ushort2 u3 = yv[(long long)b3.x * 64 + lane];
    float w0 = __int_as_float(b0.y), w1 = __int_as_float(b1.y);
    float w2 = __int_as_float(b2.y), w3 = __int_as_float(b3.y);
    ax += w0 * __uint_as_float((unsigned)u0.x << 16) +
          w1 * __uint_as_float((unsigned)u1.x << 16) +
          w2 * __uint_as_float((unsigned)u2.x << 16) +
          w3 * __uint_as_float((unsigned)u3.x << 16);
    ay += w0 * __uint_as_float((unsigned)u0.y << 16) +
          w1 * __uint_as_float((unsigned)u1.y << 16) +
          w2 * __uint_as_float((unsigned)u2.y << 16) +
          w3 * __uint_as_float((unsigned)u3.y << 16);
  }
  for (; i < cnt; i++) {
    int2 b0 = bucket[start + i];
    float w0 = __int_as_float(b0.y);
    ushort2 u0 = yv[(long long)b0.x * 64 + lane];
    ax += w0 * __uint_as_float((unsigned)u0.x << 16);
    ay += w0 * __uint_as_float((unsigned)u0.y << 16);
  }
  float2 bb = ((const float2*)b)[lane];
  float2 o = {ax + bb.x, ay + bb.y};
  ((float2*)out)[(long long)node * 64 + lane] = o;
}

extern "C" void kernel_launch(void* const* d_in, const int* in_sizes, int n_in,
                              void* d_out, int out_size, void* d_ws,
                              size_t ws_size, hipStream_t stream) {
  const float* x = (const float*)d_in[0];
  const int* ei = (const int*)d_in[1];
  const float* ew = (const float*)d_in[2];
  const float* W = (const float*)d_in[3];
  const float* b = (const float*)d_in[4];

  int N = in_sizes[0] / D;  // 100000
  int E = in_sizes[2];      // 1600000
  int NB = (N + 255) / 256;
  int Npad = NB * 256;

  // Workspace: deg | offs | cursor | blockSums | bucket (int2) | y (bf16)
  int* deg = (int*)d_ws;
  int* offs = deg + Npad;
  int* cursor = offs + Npad;
  int* blockSums = cursor + Npad;
  int2* bucket = (int2*)(blockSums + 512);
  ushort* y = (ushort*)(bucket + E);

  hipMemsetAsync(deg, 0, (size_t)Npad * sizeof(int), stream);

  int GB = (N + RT - 1) / RT;   // 1563 gemm blocks
  int HB = (E + 255) / 256;     // 6250 hist blocks
  k1_gemm_hist<<<GB + HB, 256, 0, stream>>>(x, W, y, ei, deg, N, E, GB);
  scan_block<<<NB, 256, 0, stream>>>(deg, offs, blockSums, N);
  scan_finish<<<NB, 256, 0, stream>>>(offs, blockSums, cursor, N);
  fill_bucket<<<(E + 255) / 256, 256, 0, stream>>>(ei, ew, cursor, bucket, E);
  gather_kernel<<<(N + 3) / 4, 256, 0, stream>>>(y, bucket, offs, deg, b,
                                                 (float*)d_out, N);
}